// Round 1
// baseline (198.871 us; speedup 1.0000x reference)
//
#include <hip/hip_runtime.h>
#include <math.h>

// Problem constants
#define NMAPS   7680   // (BS*NUM_CAMS=384) * N_JOINTS=20
#define BSZ     64
#define NCAMS   6
#define NJ      20

// Output layout (flat float32, reference return order)
#define OFF_KP3D 0        // (64,20,3)   = 3840
#define OFF_RES  3840     // (64,20)     = 1280
#define OFF_KPC  5120     // (64,6,20,3) = 23040
#define OFF_KPH  28160    // (64,6,20,3) = 23040

typedef float floatx4 __attribute__((ext_vector_type(4)));

// One WAVE per (n, j) heatmap of 64*64=4096 floats; 4 maps per 256-thread block.
// No LDS, no __syncthreads — all reductions are 6-stage wave butterflies.
// Lane reads float4 at element addr 4*(lane + 64*i), i=0..15 (16 KB/wave, coalesced).
// Element index idx = 4*lane + 256*i + k decomposes exactly:
//   col = idx & 63 = 4*(lane&15) + k     (independent of i)
//   row = idx >> 6 = (lane>>4) + 4*i     (independent of k)
// so weighted sums need only 5 fp32 per-thread accumulators; fp64 is used solely
// for the order-insensitive cross-lane reduction (still >= fp32-reference accuracy).
__global__ __launch_bounds__(256) void kp_kernel(const float* __restrict__ hm,
                                                 float* __restrict__ out) {
    const int wave = threadIdx.x >> 6;
    const int lane = threadIdx.x & 63;
    const int map  = blockIdx.x * 4 + wave;          // grid = NMAPS/4
    const floatx4* base = (const floatx4*)(hm + (size_t)map * 4096);

    // Plain (cacheable) loads: the 126 MB input fits in the 256 MB Infinity Cache,
    // so it can stay L3-resident across graph replays (NT hint forbade that).
    floatx4 v[16];
#pragma unroll
    for (int i = 0; i < 16; i++) v[i] = base[lane + 64 * i];

    // Pass 1: wave max (in-register, butterfly so every lane holds it)
    float m = v[0].x;
#pragma unroll
    for (int i = 0; i < 16; i++)
        m = fmaxf(m, fmaxf(fmaxf(v[i].x, v[i].y), fmaxf(v[i].z, v[i].w)));
#pragma unroll
    for (int off = 32; off > 0; off >>= 1)
        m = fmaxf(m, __shfl_xor(m, off, 64));
    const float hmax = 100.0f * m;

    // Pass 2: per-thread fp32 partials (values <= 1, <= 64 terms: ~1e-7 rel err)
    float ek0 = 0.f, ek1 = 0.f, ek2 = 0.f, ek3 = 0.f;  // per-k column sums
    float si  = 0.f;                                    // sum_i i * se_i
#pragma unroll
    for (int i = 0; i < 16; i++) {
        const float e0 = __expf(100.0f * v[i].x - hmax);
        const float e1 = __expf(100.0f * v[i].y - hmax);
        const float e2 = __expf(100.0f * v[i].z - hmax);
        const float e3 = __expf(100.0f * v[i].w - hmax);
        ek0 += e0; ek1 += e1; ek2 += e2; ek3 += e3;
        const float se_i = (e0 + e1) + (e2 + e3);
        si = fmaf((float)i, se_i, si);
    }

    // Assemble the three weighted sums in fp64, reduce across the wave in fp64.
    const double dk0 = (double)ek0, dk1 = (double)ek1;
    const double dk2 = (double)ek2, dk3 = (double)ek3;
    double se = (dk0 + dk1) + (dk2 + dk3);
    double sx = (double)(4 * (lane & 15)) * se + (dk1 + 2.0 * dk2 + 3.0 * dk3);
    double sy = (double)(lane >> 4) * se + 4.0 * (double)si;
#pragma unroll
    for (int off = 32; off > 0; off >>= 1) {
        se += __shfl_xor(se, off, 64);
        sx += __shfl_xor(sx, off, 64);
        sy += __shfl_xor(sy, off, 64);
    }

    if (lane == 0) {
        const float x    = (float)(sx / se);
        const float y    = (float)(sy / se);
        const float conf = (float)(1.0 / se);   // max(softmax)/sum(softmax)
        const int o = map * 3;
        out[OFF_KPH + o + 0] = x;
        out[OFF_KPH + o + 1] = y;
        out[OFF_KPH + o + 2] = conf;
        out[OFF_KPC + o + 0] = 4.0f * x;        // * (H_IMG/H_MAP)
        out[OFF_KPC + o + 1] = 4.0f * y;        // * (W_IMG/W_MAP)
        out[OFF_KPC + o + 2] = conf;
    }
}

// One thread per (bs, j): build 12x4 A, eigensolve A^T A (fp64 Jacobi),
// null vector -> kp_3d and residual.  (Math unchanged — proven correct.)
__global__ __launch_bounds__(64) void tri_kernel(const float* __restrict__ proj,
                                                 const float* __restrict__ confin,
                                                 float* __restrict__ out) {
    const int t = blockIdx.x * blockDim.x + threadIdx.x;
    if (t >= BSZ * NJ) return;
    const int bs = t / NJ, j = t % NJ;

    // Normalized per-camera confidences: c/sum + 1e-5
    float cn[NCAMS];
    float csum = 0.0f;
#pragma unroll
    for (int c = 0; c < NCAMS; c++) {
        cn[c] = confin[(bs * NCAMS + c) * NJ + j];
        csum += cn[c];
    }
#pragma unroll
    for (int c = 0; c < NCAMS; c++) cn[c] = cn[c] / csum + 1e-5f;

    // A[(cam*2+r)][k] = (P[cam][2][k]*pt_r - P[cam][r][k]) * cn[cam]  (fp32, as ref)
    float A[12][4];
#pragma unroll
    for (int c = 0; c < NCAMS; c++) {
        const float* P = proj + ((size_t)bs * NCAMS + c) * 12;
        const int kidx = OFF_KPC + ((bs * NCAMS + c) * NJ + j) * 3;
        const float px = out[kidx + 0];
        const float py = out[kidx + 1];
#pragma unroll
        for (int k = 0; k < 4; k++) {
            const float r2 = P[8 + k];
            A[c * 2 + 0][k] = (r2 * px - P[k])     * cn[c];
            A[c * 2 + 1][k] = (r2 * py - P[4 + k]) * cn[c];
        }
    }

    // M = A^T A in fp64
    double M[4][4], V[4][4];
    double diagmax = 0.0;
#pragma unroll
    for (int a = 0; a < 4; a++)
#pragma unroll
        for (int b2 = a; b2 < 4; b2++) {
            double s = 0.0;
#pragma unroll
            for (int n = 0; n < 12; n++) s += (double)A[n][a] * (double)A[n][b2];
            M[a][b2] = s; M[b2][a] = s;
            if (a == b2) diagmax = fmax(diagmax, fabs(s));
        }
#pragma unroll
    for (int a = 0; a < 4; a++)
#pragma unroll
        for (int b2 = 0; b2 < 4; b2++) V[a][b2] = (a == b2) ? 1.0 : 0.0;

    // Cyclic Jacobi, 6 sweeps (4x4 off-diag hits fp64 eps in ~4; 6 = margin).
    const double skip_tol = diagmax * 1e-18;
    for (int sweep = 0; sweep < 6; sweep++) {
#pragma unroll
        for (int p = 0; p < 3; p++)
#pragma unroll
            for (int q2 = p + 1; q2 < 4; q2++) {
                const double apq = M[p][q2];
                if (fabs(apq) <= skip_tol) continue;
                const double tau = (M[q2][q2] - M[p][p]) / (2.0 * apq);
                const double tt  = (tau >= 0.0 ? 1.0 : -1.0) /
                                   (fabs(tau) + sqrt(1.0 + tau * tau));
                const double c   = 1.0 / sqrt(1.0 + tt * tt);
                const double s   = tt * c;
#pragma unroll
                for (int k = 0; k < 4; k++) {          // right-mult columns p,q
                    const double mkp = M[k][p], mkq = M[k][q2];
                    M[k][p]  = c * mkp - s * mkq;
                    M[k][q2] = s * mkp + c * mkq;
                }
#pragma unroll
                for (int k = 0; k < 4; k++) {          // left-mult rows p,q
                    const double mpk = M[p][k], mqk = M[q2][k];
                    M[p][k]  = c * mpk - s * mqk;
                    M[q2][k] = s * mpk + c * mqk;
                }
#pragma unroll
                for (int k = 0; k < 4; k++) {          // accumulate eigenvectors
                    const double vkp = V[k][p], vkq = V[k][q2];
                    V[k][p]  = c * vkp - s * vkq;
                    V[k][q2] = s * vkp + c * vkq;
                }
            }
    }

    // Min-eigenvalue column = homogeneous solution (sign-free: outputs invariant)
    int mi = 0;
#pragma unroll
    for (int i = 1; i < 4; i++)
        if (M[i][i] < M[mi][mi]) mi = i;
    const double h0 = V[0][mi], h1 = V[1][mi], h2 = V[2][mi], h3 = V[3][mi];

    out[OFF_KP3D + t * 3 + 0] = (float)(h0 / h3);
    out[OFF_KP3D + t * 3 + 1] = (float)(h1 / h3);
    out[OFF_KP3D + t * 3 + 2] = (float)(h2 / h3);

    const float hf0 = (float)h0, hf1 = (float)h1, hf2 = (float)h2, hf3 = (float)h3;
    float res = 0.0f;
#pragma unroll
    for (int n = 0; n < 12; n++)
        res += fabsf(A[n][0] * hf0 + A[n][1] * hf1 + A[n][2] * hf2 + A[n][3] * hf3);
    out[OFF_RES + t] = res;
}

extern "C" void kernel_launch(void* const* d_in, const int* in_sizes, int n_in,
                              void* d_out, int out_size, void* d_ws, size_t ws_size,
                              hipStream_t stream) {
    const float* heatmap = (const float*)d_in[0];   // (384,20,64,64)
    const float* proj    = (const float*)d_in[1];   // (64,6,3,4)
    const float* confid  = (const float*)d_in[2];   // (384,20)
    float* out = (float*)d_out;                     // 51200 floats

    // 4 maps (4 waves) per block, one wave per map.
    hipLaunchKernelGGL(kp_kernel, dim3(NMAPS / 4), dim3(256), 0, stream, heatmap, out);
    // 1280 independent threads: 20 blocks x 64 -> one wave on each of 20 CUs.
    hipLaunchKernelGGL(tri_kernel, dim3((BSZ * NJ + 63) / 64), dim3(64), 0, stream,
                       proj, confid, out);
}